// Round 5
// baseline (60.332 us; speedup 1.0000x reference)
//
#include <hip/hip_runtime.h>
#include <hip/hip_bf16.h>
#include <stdint.h>

#define N 8192
#define D 256
#define ROWB 256                      // rows per simlse block (4 waves x 64)
#define COLG 16                       // column groups
#define COLS_PER_BLK (N / COLG)       // 512
#define TILE_N 32
#define NT (COLS_PER_BLK / TILE_N)    // 16
#define TILE_BYTES (TILE_N * D * 2)   // 16384 B
#define NBUF 4                        // 64 KB LDS ring
#define E_CONST 2.71828182845904523536f
#define LOG2E 1.44269504088896340736f

typedef __attribute__((ext_vector_type(8))) short bf16x8;   // 8 bf16 (4 VGPRs)
typedef __attribute__((ext_vector_type(4))) float f32x4;

__device__ inline float bf2f(unsigned short u) {
  union { unsigned int i; float f; } c; c.i = ((unsigned)u) << 16; return c.f;
}
__device__ inline unsigned short f2bf(float x) {
  union { float f; unsigned int i; } c; c.f = x;
  unsigned int r = (c.i + 0x7fffu + ((c.i >> 16) & 1u)) >> 16;
  return (unsigned short)r;
}

typedef const __attribute__((address_space(1))) void gvoid_t;
typedef __attribute__((address_space(3))) void lvoid_t;
__device__ inline void gload_lds16(const void* g, void* l) {
  __builtin_amdgcn_global_load_lds((gvoid_t*)g, (lvoid_t*)l, 16, 0, 0);
}

// ---- kernel 1: row L2-normalize, fp32 -> bf16 (plain + log2e-scaled copies) ----
__global__ __launch_bounds__(256) void norm_kernel(const float* __restrict__ feat,
                                                   unsigned short* __restrict__ fbf,
                                                   unsigned short* __restrict__ fbfA) {
  int wave = threadIdx.x >> 6, lane = threadIdx.x & 63;
  int row = blockIdx.x * 4 + wave;
  const float4 v = *(const float4*)(feat + (size_t)row * D + lane * 4);
  float ss = v.x * v.x + v.y * v.y + v.z * v.z + v.w * v.w;
  for (int m = 1; m < 64; m <<= 1) ss += __shfl_xor(ss, m, 64);
  float rn = 1.0f / fmaxf(sqrtf(ss), 1e-12f);
  ushort4 o;
  o.x = f2bf(v.x * rn); o.y = f2bf(v.y * rn);
  o.z = f2bf(v.z * rn); o.w = f2bf(v.w * rn);
  *(ushort4*)(fbf + (size_t)row * D + lane * 4) = o;
  float rl = rn * LOG2E;
  ushort4 oa;
  oa.x = f2bf(v.x * rl); oa.y = f2bf(v.y * rl);
  oa.z = f2bf(v.z * rl); oa.w = f2bf(v.w * rl);
  *(ushort4*)(fbfA + (size_t)row * D + lane * 4) = oa;
}

// ---- kernel 2: positive-pair dot (unscaled normalized rows) ----
__global__ __launch_bounds__(256) void pos_kernel(const unsigned short* __restrict__ fbf,
                                                  float* __restrict__ pos) {
  int wave = threadIdx.x >> 6, lane = threadIdx.x & 63;
  int row = blockIdx.x * 4 + wave;
  int partner = (row < N / 2) ? row + N / 2 : row - N / 2;
  const ushort4 a = *(const ushort4*)(fbf + (size_t)row * D + lane * 4);
  const ushort4 b = *(const ushort4*)(fbf + (size_t)partner * D + lane * 4);
  float d = bf2f(a.x) * bf2f(b.x) + bf2f(a.y) * bf2f(b.y) +
            bf2f(a.z) * bf2f(b.z) + bf2f(a.w) * bf2f(b.w);
  for (int m = 1; m < 64; m <<= 1) d += __shfl_xor(d, m, 64);
  if (lane == 0) pos[row] = d;
}

// ---- kernel 3: fused sim tile + partial sum(2^(sim*log2e)) = sum(exp(sim)) ----
// M=64 rows/wave; 4-deep LDS ring; one barrier/tile; counted vmcnt; slab output.
__global__ __launch_bounds__(256, 2) void simlse_kernel(const unsigned short* __restrict__ fbfA,
                                                        const unsigned short* __restrict__ fbf,
                                                        float* __restrict__ partial) {
  __shared__ char lds[NBUF * TILE_BYTES];   // 64 KB
  const char* fb = (const char*)fbf;
  const char* fa = (const char*)fbfA;
  int tid = threadIdx.x;
  int wave = tid >> 6, lane = tid & 63;
  int l15 = lane & 15, lhi = lane >> 4;
  int rb = blockIdx.x >> 4;   // 0..31
  int cg = blockIdx.x & 15;   // 0..15

  // A fragments (log2e-scaled): 4 m-tiles (64 rows/wave) x 8 k-steps, pinned
  bf16x8 a[4][8];
  int rowbase = rb * ROWB + wave * 64;
#pragma unroll
  for (int mt = 0; mt < 4; ++mt) {
    size_t ar = (size_t)(rowbase + mt * 16 + l15) * 512;
#pragma unroll
    for (int ks = 0; ks < 8; ++ks)
      a[mt][ks] = *(const bf16x8*)(fa + ar + lhi * 16 + ks * 64);
  }
#pragma unroll
  for (int mt = 0; mt < 4; ++mt)
#pragma unroll
    for (int ks = 0; ks < 8; ++ks)
      asm volatile("" : "+v"(a[mt][ks]));   // forbid rematerialization / sinking

  float s[4][4];
#pragma unroll
  for (int mt = 0; mt < 4; ++mt)
#pragma unroll
    for (int r = 0; r < 4; ++r) s[mt][r] = 0.0f;

  // staging: 256 threads x 16B x 4 passes = one 16 KB tile; XOR-swizzled source
  int colbase = cg * COLS_PER_BLK;
  int lrow0 = tid >> 5;                                        // 0..7
  int goff = ((tid & 31) * 16) ^ (((tid >> 5) & 7) << 4);      // same for all passes

#define STAGE(tt)                                                               \
  {                                                                             \
    char* stg = lds + ((tt) & (NBUF - 1)) * TILE_BYTES + wave * 1024;           \
    size_t cb = (size_t)(colbase + (tt) * TILE_N) * 512;                        \
    _Pragma("unroll")                                                           \
    for (int p = 0; p < 4; ++p)                                                 \
      gload_lds16(fb + cb + (size_t)(lrow0 + p * 8) * 512 + goff,               \
                  stg + p * 4096);                                              \
  }

  STAGE(0);
  STAGE(1);

  for (int t = 0; t < NT; ++t) {
    if (t + 2 < NT) {
      STAGE(t + 2);                       // ring distance 3 from any live reader
      asm volatile("s_waitcnt vmcnt(8)" ::: "memory");  // tile t landed
    } else if (t + 1 < NT) {
      asm volatile("s_waitcnt vmcnt(4)" ::: "memory");
    } else {
      asm volatile("s_waitcnt vmcnt(0)" ::: "memory");
    }
    __builtin_amdgcn_sched_barrier(0);
    __builtin_amdgcn_s_barrier();         // all waves' chunks of tile t visible
    __builtin_amdgcn_sched_barrier(0);

    const char* bb = lds + (t & (NBUF - 1)) * TILE_BYTES;
    int rswz = (l15 & 7) << 4;
#pragma unroll
    for (int ct = 0; ct < 2; ++ct) {
      f32x4 acc0 = {0,0,0,0}, acc1 = {0,0,0,0}, acc2 = {0,0,0,0}, acc3 = {0,0,0,0};
      const char* br = bb + (ct * 16 + l15) * 512;
#pragma unroll
      for (int ks = 0; ks < 8; ++ks) {
        int kb = lhi * 16 + ks * 64;
        bf16x8 bfrag = *(const bf16x8*)(br + (kb ^ rswz));
        acc0 = __builtin_amdgcn_mfma_f32_16x16x32_bf16(a[0][ks], bfrag, acc0, 0, 0, 0);
        acc1 = __builtin_amdgcn_mfma_f32_16x16x32_bf16(a[1][ks], bfrag, acc1, 0, 0, 0);
        acc2 = __builtin_amdgcn_mfma_f32_16x16x32_bf16(a[2][ks], bfrag, acc2, 0, 0, 0);
        acc3 = __builtin_amdgcn_mfma_f32_16x16x32_bf16(a[3][ks], bfrag, acc3, 0, 0, 0);
      }
#pragma unroll
      for (int r = 0; r < 4; ++r) {
        s[0][r] += __builtin_exp2f(acc0[r]);
        s[1][r] += __builtin_exp2f(acc1[r]);
        s[2][r] += __builtin_exp2f(acc2[r]);
        s[3][r] += __builtin_exp2f(acc3[r]);
      }
    }
  }
#undef STAGE

  // row-wise reduce across the 16 lanes holding each row's columns
#pragma unroll
  for (int mt = 0; mt < 4; ++mt)
#pragma unroll
    for (int r = 0; r < 4; ++r)
      for (int m = 1; m < 16; m <<= 1)
        s[mt][r] += __shfl_xor(s[mt][r], m, 64);

  if (l15 == 0) {
#pragma unroll
    for (int mt = 0; mt < 4; ++mt)
#pragma unroll
      for (int r = 0; r < 4; ++r)
        partial[(size_t)cg * N + rowbase + mt * 16 + lhi * 4 + r] = s[mt][r];
  }
}

// ---- kernel 4: combine slab partials -> scalar loss ----
__global__ __launch_bounds__(1024) void final_kernel(const float* __restrict__ partial,
                                                     const float* __restrict__ pos,
                                                     float* __restrict__ out) {
  int tid = threadIdx.x;
  float acc = 0.0f;
  for (int i = tid; i < N; i += 1024) {
    float ssum = 0.0f;
#pragma unroll
    for (int c = 0; c < COLG; ++c) ssum += partial[(size_t)c * N + i];
    float sv = ssum - E_CONST;              // remove diag exp(sim_ii) ~= e
    acc += __logf(sv) - pos[i];
  }
  __shared__ float red[16];
  for (int m = 1; m < 64; m <<= 1) acc += __shfl_xor(acc, m, 64);
  int wave = tid >> 6, lane = tid & 63;
  if (lane == 0) red[wave] = acc;
  __syncthreads();
  if (tid == 0) {
    float t = 0.0f;
#pragma unroll
    for (int w = 0; w < 16; ++w) t += red[w];
    out[0] = t / (float)N;
  }
}

extern "C" void kernel_launch(void* const* d_in, const int* in_sizes, int n_in,
                              void* d_out, int out_size, void* d_ws, size_t ws_size,
                              hipStream_t stream) {
  const float* feat = (const float*)d_in[0];
  unsigned short* fbf  = (unsigned short*)d_ws;                                  // 4 MB
  unsigned short* fbfA = (unsigned short*)((char*)d_ws + (size_t)N * D * 2);     // 4 MB
  float* pos = (float*)((char*)d_ws + (size_t)2 * N * D * 2);                    // 32 KB
  float* partial = (float*)((char*)d_ws + (size_t)2 * N * D * 2 + (size_t)N * 4);// 512 KB
  float* out = (float*)d_out;

  norm_kernel<<<N / 4, 256, 0, stream>>>(feat, fbf, fbfA);
  pos_kernel<<<N / 4, 256, 0, stream>>>(fbf, pos);
  simlse_kernel<<<(N / ROWB) * COLG, 256, 0, stream>>>(fbfA, fbf, partial);
  final_kernel<<<1, 1024, 0, stream>>>(partial, pos, out);
}